// Round 3
// baseline (39.495 us; speedup 1.0000x reference)
//
#include <hip/hip_runtime.h>

// RankingBCELoss: loss = (1/(n_pos*n_neg)) * sum_{p,n} log(1 + e^{x_n} * e^{-x_p})
// en = exp(x_neg), emp = exp(-x_pos) precomputed once (order-permuted compaction:
// the pair sum is order-independent, so any deterministic packing works).
// Per pair: t = fma(en, emp, 1); product-of-8 terms then one v_log_f32.
// Sum in log2 units, scale by ln2 at the end.
// 2 kernels total: compact, then pair (+ last-block-done finalize, no 3rd launch).

#define N_MAX 16384
#define CB 1024            // compact block threads (single block)
#define TP 16              // positives per pair block
#define PT 256             // pair kernel threads
#define CHUNK 8192         // floats staged per LDS chunk (32 KB)

// ---- Kernel 1: compaction + exp precompute (single block, coalesced) ------
__global__ __launch_bounds__(CB)
void compact_kernel(const float* __restrict__ x, const int* __restrict__ tg,
                    int n, float* __restrict__ pos_emp, float* __restrict__ neg_en,
                    int* __restrict__ cnts, unsigned int* __restrict__ done) {
    __shared__ float sbuf[N_MAX];       // pos from front, neg from back
    __shared__ int swsum[16], swoff[16], stot;
    const int tid  = threadIdx.x;
    const int lane = tid & 63, wid = tid >> 6;
    const int n4 = n >> 2;              // n == 16384: 4096 float4s, 4 per thread

    // Coalesced vectorized loads: lane-consecutive float4/int4 (16 B/lane).
    float4 vf[4]; int4 vt[4];
    int lp = 0, ln = 0;
#pragma unroll
    for (int k = 0; k < 4; ++k) {
        const int i4 = tid + k * CB;
        if (i4 < n4) { vf[k] = ((const float4*)x)[i4]; vt[k] = ((const int4*)tg)[i4]; }
        else         { vf[k] = make_float4(0,0,0,0); vt[k] = make_int4(-1,-1,-1,-1); }
        lp += (vt[k].x==1) + (vt[k].y==1) + (vt[k].z==1) + (vt[k].w==1);
        ln += (vt[k].x==0) + (vt[k].y==0) + (vt[k].z==0) + (vt[k].w==0);
    }

    // packed (pos | neg<<16) inclusive wave scan, then cross-wave scan
    const int c = lp | (ln << 16);
    int inc = c;
#pragma unroll
    for (int off = 1; off < 64; off <<= 1) {
        int u = __shfl_up(inc, off, 64);
        if (lane >= off) inc += u;
    }
    if (lane == 63) swsum[wid] = inc;
    __syncthreads();
    if (tid < 16) {
        int val = swsum[tid];
        int sc = val;
#pragma unroll
        for (int off = 1; off < 16; off <<= 1) {
            int u = __shfl_up(sc, off, 64);
            if (tid >= off) sc += u;
        }
        swoff[tid] = sc - val;          // exclusive wave offset
        if (tid == 15) stot = sc;       // packed totals
    }
    __syncthreads();
    const int ex = swoff[wid] + (inc - c);   // exclusive thread prefix (packed)
    int op = ex & 0xffff;
    int on = ex >> 16;
#pragma unroll
    for (int k = 0; k < 4; ++k) {
        const float vv[4] = {vf[k].x, vf[k].y, vf[k].z, vf[k].w};
        const int   tt[4] = {vt[k].x, vt[k].y, vt[k].z, vt[k].w};
#pragma unroll
        for (int j = 0; j < 4; ++j) {
            if (tt[j] == 1)      sbuf[op++]           = __expf(-vv[j]);  // e^{-x_pos}
            else if (tt[j] == 0) sbuf[n - 1 - (on++)] = __expf(vv[j]);   // e^{x_neg}
        }
    }
    __syncthreads();
    const int np = stot & 0xffff;
    const int nn = stot >> 16;
    const int nn_pad = (nn + 127) & ~127;
    for (int i = tid; i < np; i += CB)          pos_emp[i] = sbuf[i];
    for (int i = tid; i < nn; i += CB)          neg_en[i]  = sbuf[n - 1 - i];
    for (int i = nn + tid; i < nn_pad; i += CB) neg_en[i]  = 0.f;  // pad: fma(0,emp,1)=1 -> log 0
    if (tid == 0) { cnts[0] = np; cnts[1] = nn; cnts[2] = nn_pad; *done = 0u; }
}

// ---- Kernel 2: pairwise accumulation + last-block finalize ----------------
__global__ __launch_bounds__(PT)
void pair_kernel(const float* __restrict__ pos_emp, const float* __restrict__ neg_en,
                 const int* __restrict__ cnts, double* __restrict__ partials,
                 unsigned int* __restrict__ done, int nblocks, float* __restrict__ out) {
    const int np = cnts[0], nn_pad = cnts[2];
    const int bid = blockIdx.x, tid = threadIdx.x;
    const int pbase = bid * TP;
    const bool active = (pbase < np) && (nn_pad > 0);   // block-uniform

    __shared__ float lds[CHUNK];
    float accf = 0.0f;
    if (active) {
        const int pl = tid & (TP - 1);
        const int nt = tid >> 4;                    // 0..15
        const int p  = pbase + pl;
        const float emp = (p < np) ? pos_emp[p] : 0.0f;  // OOR -> all terms 1 -> contributes 0
        for (int cb = 0; cb < nn_pad; cb += CHUNK) {
            const int cnt = min(CHUNK, nn_pad - cb);     // multiple of 128
            __syncthreads();
            const float4* src = (const float4*)(neg_en + cb);
            float4*       dst = (float4*)lds;
            for (int i = tid; i < (cnt >> 2); i += PT) dst[i] = src[i];
            __syncthreads();
            const int nb = nt * 4;
            // 8 pairs -> 2x ds_read_b128 (broadcast within pl-group), 8 fma,
            // 7 mul, 1 log2, 1 add. Max product ~5e4^8 < f32 max: safe.
            for (int jb = 0; jb < cnt; jb += 128) {
                const float4 a = *(const float4*)&lds[jb + nb];
                const float4 b = *(const float4*)&lds[jb + 64 + nb];
                float p0 = __builtin_fmaf(a.x, emp, 1.0f);
                float p1 = __builtin_fmaf(a.y, emp, 1.0f);
                p0 *= __builtin_fmaf(a.z, emp, 1.0f);
                p1 *= __builtin_fmaf(a.w, emp, 1.0f);
                p0 *= __builtin_fmaf(b.x, emp, 1.0f);
                p1 *= __builtin_fmaf(b.y, emp, 1.0f);
                p0 *= __builtin_fmaf(b.z, emp, 1.0f);
                p1 *= __builtin_fmaf(b.w, emp, 1.0f);
                accf += __log2f(p0 * p1);
            }
        }
    }

    // block reduction -> per-block partial (no cross-block atomics on data)
    float s = accf;
    for (int off = 32; off > 0; off >>= 1) s += __shfl_down(s, off, 64);
    __shared__ double wsum[PT / 64];
    if ((tid & 63) == 0) wsum[tid >> 6] = (double)s;
    __syncthreads();

    __shared__ bool amLast;
    if (tid == 0) {
        double b = 0.0;
#pragma unroll
        for (int w = 0; w < PT / 64; ++w) b += wsum[w];
        partials[bid] = b;
        __threadfence();                              // release: partial visible device-wide
        amLast = (atomicAdd(done, 1u) == (unsigned)(nblocks - 1));
    }
    __syncthreads();

    if (amLast) {                                     // block-uniform
        __threadfence();                              // acquire before reading partials
        double d = 0.0;
        for (int i = tid; i < nblocks; i += PT)
            d += *((volatile const double*)(partials + i));
        for (int off = 32; off > 0; off >>= 1) d += __shfl_down(d, off, 64);
        __shared__ double fsum[PT / 64];
        if ((tid & 63) == 0) fsum[tid >> 6] = d;
        __syncthreads();
        if (tid == 0) {
            double ssum = 0.0;
#pragma unroll
            for (int w = 0; w < PT / 64; ++w) ssum += fsum[w];
            const double npairs = (double)cnts[0] * (double)cnts[1];
            out[0] = (npairs > 0.0) ? (float)(ssum * 0.6931471805599453 / npairs) : 0.0f;
        }
    }
}

extern "C" void kernel_launch(void* const* d_in, const int* in_sizes, int n_in,
                              void* d_out, int out_size, void* d_ws, size_t ws_size,
                              hipStream_t stream) {
    const float* x  = (const float*)d_in[0];
    const int*   tg = (const int*)d_in[1];
    const int n = in_sizes[0];                 // 16384

    char* ws = (char*)d_ws;
    float*        pos_emp  = (float*)(ws);             // 64 KB
    float*        neg_en   = (float*)(ws + 65536);     // 64 KB (incl. zero pad)
    int*          cnts     = (int*)(ws + 131072);      // 3 ints
    unsigned int* done     = (unsigned int*)(ws + 131200);
    double*       partials = (double*)(ws + 131328);   // nblocks doubles

    const int nblocks = (n + TP - 1) / TP;     // 1024
    compact_kernel<<<1, CB, 0, stream>>>(x, tg, n, pos_emp, neg_en, cnts, done);
    pair_kernel<<<nblocks, PT, 0, stream>>>(pos_emp, neg_en, cnts, partials, done,
                                            nblocks, (float*)d_out);
}